// Round 7
// baseline (471.079 us; speedup 1.0000x reference)
//
#include <hip/hip_runtime.h>

// toy_gnn scatter-add: out[dst[e], f] += w_mp * edge_weight[e] * x[src[e], f]
// N=100000, E=1600000, F=32, fp32.
//
// Round 14: direct LDS-atomic accumulate gather (no sort, no imbalance).
//   Window model (calibrated on R12: window 313 - kernel 243 = 70us fixed):
//   268MB workspace re-poison fill (43us, in-window, hbm_bytes confirms) +
//   memset + gaps = ~70us fixed; bin+gather = ~50us total. Six flat rounds
//   = +-5us effects on a 50us kernel budget. R13 falsified load-pipeline
//   depth; remaining gather fat is STRUCTURE: 3 serialized phases (hist ->
//   scan -> scatter) + per-node drain loop where a wave waits on the max
//   degree of its 8 nodes (~40-50% idle lanes) + 5 syncthreads.
//   Change: replace sort_gather with scatter_lds -- one striped pass over
//   records in arrival order; each 8-lane group loads 16B of the x-row and
//   ds_add_f32's 4 floats into tile[256][36] (stride-36 pad: bank =
//   4*((dl+lane8)%8), random dl -> ~2-way conflicts, vs 8-way at stride 32).
//   R6's lesson applied correctly: R6 used a GENERIC pointer (flat atomic
//   CAS disaster); direct static __shared__ indexing emits native ds_add.
//   Zero imbalance, zero sort machinery, 2 barriers total, 8-deep batches.
//   Epilogue: coalesced float4 tile->out. Bin kernel untouched (proven
//   equal across R9/R11/R13 variants).
//   Kept: R4 coarse layout, contiguous per-bucket records (R9), coalesced
//   bin writes (R11), one code path (R10), predicated sentinel tail (R13).

constexpr int N_NODES = 100000;
constexpr int N_EDGES = 1600000;
constexpr int F_DIM   = 32;

// ---- binning (coarse) ----
constexpr int NPB_C = 256;                           // nodes per coarse bucket
constexpr int NB_C  = (N_NODES + NPB_C - 1) / NPB_C; // 391
constexpr int CAP_C = 4608;                          // mean 4096 + 8 sigma(64)

constexpr int CUR_STRIDE = 32;                       // ints; 128B per cursor line

constexpr int BIN_THREADS = 1024;
constexpr int BIN_BLOCKS  = 512;                     // 2 blocks/CU
constexpr int BIN_CHUNK   = N_EDGES / BIN_BLOCKS;    // 3125 (exact: 512*3125)
constexpr int BIN_EPT     = (BIN_CHUNK + BIN_THREADS - 1) / BIN_THREADS;  // 4

// ---- gather ----
constexpr int AGG_THREADS = 512;                     // 8 waves; 2 blocks/CU
constexpr int TSTRIDE = F_DIM + 4;                   // 36 floats: bank spread

// ---------------- workspace layout (bytes) ----------------
constexpr size_t WS_CURSOR  = 0;                     // NB_C padded cursors
constexpr size_t WS_RECORDS = 64 * 1024;             // NB_C*CAP_C uint2
constexpr size_t WS_NEEDED  = WS_RECORDS + (size_t)NB_C * CAP_C * 8;  // ~14.5 MB
constexpr size_t WS_ZERO    = (size_t)NB_C * CUR_STRIDE * 4;          // ~50 KB

__global__ __launch_bounds__(BIN_THREADS, 8) void bin_edges(
    const int* __restrict__ src, const int* __restrict__ dst,
    const float* __restrict__ ew, const float* __restrict__ w_mp,
    int* __restrict__ gcursor, uint2* __restrict__ records)
{
    __shared__ uint2 srt[BIN_CHUNK];                 // 25 KB block-sorted recs
    __shared__ unsigned short srtb[BIN_CHUNK];       // 6.25 KB bucket tag
    __shared__ int lhist[NB_C];
    __shared__ int loff[NB_C];                       // excl prefix within block
    __shared__ int lbase[NB_C];                      // global base - loff
    __shared__ int lcur[NB_C];
    __shared__ int wsum[8];
    __shared__ int wexc[8];

    const int t    = threadIdx.x;
    const int lane = t & 63;
    const int wv   = t >> 6;

    if (t < NB_C) lhist[t] = 0;
    __syncthreads();

    // --- load chunk into registers, histogram buckets ---
    const float w = w_mp[0];
    const int e0    = blockIdx.x * BIN_CHUNK;
    const int e_end = min(e0 + BIN_CHUNK, N_EDGES);
    const int cnt   = e_end - e0;

    int   bkt[BIN_EPT];
    uint2 rec[BIN_EPT];
    #pragma unroll
    for (int i = 0; i < BIN_EPT; ++i) {
        int j = t + i * BIN_THREADS;
        bkt[i] = -1;
        if (j < cnt) {
            int e = e0 + j;
            int d = dst[e];
            int b = d >> 8;
            bkt[i] = b;
            rec[i].x = __float_as_uint(w * ew[e]);
            rec[i].y = (unsigned)src[e] | ((unsigned)(d & 255) << 24);
            atomicAdd(&lhist[b], 1);
        }
    }
    __syncthreads();

    // --- exclusive scan over 391 counters (7 waves + cross-wave fixup) ---
    if (t < 448) {
        int v = (t < NB_C) ? lhist[t] : 0;
        int inc = v;
        #pragma unroll
        for (int d = 1; d < 64; d <<= 1) {
            int o = __shfl_up(inc, d, 64);
            if (lane >= d) inc += o;
        }
        if (lane == 63) wsum[wv] = inc;
        if (t < NB_C) loff[t] = inc - v;
    }
    __syncthreads();
    if (t < 64) {
        int v = (t < 7) ? wsum[t] : 0;
        int inc = v;
        #pragma unroll
        for (int d = 1; d < 8; d <<= 1) {
            int o = __shfl_up(inc, d, 64);
            if (t >= d) inc += o;
        }
        if (t < 7) wexc[t] = inc - v;
    }
    __syncthreads();

    // --- allocate global region per bucket; fold -loff into base ---
    if (t < NB_C) {
        int off = loff[t] + wexc[t >> 6];
        int c   = lhist[t];
        int base = c ? atomicAdd(&gcursor[t * CUR_STRIDE], c) : 0;
        lbase[t] = t * CAP_C + base - off;           // addr = lbase[b] + j
        lcur[t]  = off;
    }
    __syncthreads();

    // --- scatter registers -> LDS in bucket-sorted order ---
    #pragma unroll
    for (int i = 0; i < BIN_EPT; ++i) {
        if (bkt[i] >= 0) {
            int s = atomicAdd(&lcur[bkt[i]], 1);
            srt[s]  = rec[i];
            srtb[s] = (unsigned short)bkt[i];
        }
    }
    __syncthreads();

    // --- coalesced write-out: consecutive j -> consecutive global addr ---
    for (int j = t; j < cnt; j += BIN_THREADS) {
        int b   = srtb[j];
        int pos = lbase[b] + j;
        if (pos < (b + 1) * CAP_C)                   // 8-sigma overflow guard
            records[pos] = srt[j];
    }
}

__global__ __launch_bounds__(AGG_THREADS, 4) void scatter_lds(
    const int*   __restrict__ gcursor,
    const uint2* __restrict__ records,
    const float* __restrict__ x,
    float*       __restrict__ out)
{
    // per-bucket accumulator tile; stride 36 floats spreads the 8 dword
    // columns of a row across bank groups keyed by node-in-bucket.
    __shared__ float tile[NPB_C * TSTRIDE];          // 36.9 KB

    const int coarse = blockIdx.x;
    const int t      = threadIdx.x;

    // zero tile (float4: stride 36 keeps rows 16B-aligned)
    for (int i = t; i < NPB_C * TSTRIDE / 4; i += AGG_THREADS)
        reinterpret_cast<float4*>(tile)[i] = make_float4(0.f, 0.f, 0.f, 0.f);
    __syncthreads();

    const int rbase = coarse * CAP_C;
    const int cnt   = min(gcursor[coarse * CUR_STRIDE], CAP_C);

    const int g     = t >> 3;                        // 64 record groups
    const int lane8 = t & 7;                         // float4 slot in row
    const float4* __restrict__ xv = reinterpret_cast<const float4*>(x);

    // 8-deep batches: 512 records per outer iteration, striped -> zero
    // imbalance. Sentinel {0,0} for the tail: adds 0*x[0] to tile[0].
    for (int j0 = 0; j0 < cnt; j0 += 8 * 64) {
        uint2 r[8];
        #pragma unroll
        for (int b = 0; b < 8; ++b) {
            int j = j0 + b * 64 + g;
            r[b] = (j < cnt) ? records[rbase + j] : make_uint2(0u, 0u);
        }
        float4 v[8];
        #pragma unroll
        for (int b = 0; b < 8; ++b)
            v[b] = xv[(r[b].y & 0xFFFFFFu) * 8u + lane8];
        #pragma unroll
        for (int b = 0; b < 8; ++b) {
            const float c  = __uint_as_float(r[b].x);
            const int   dl = (int)(r[b].y >> 24);
            const int   o  = dl * TSTRIDE + lane8 * 4;
            atomicAdd(&tile[o + 0], c * v[b].x);     // ds_add_f32 (native LDS)
            atomicAdd(&tile[o + 1], c * v[b].y);
            atomicAdd(&tile[o + 2], c * v[b].z);
            atomicAdd(&tile[o + 3], c * v[b].w);
        }
    }
    __syncthreads();

    // coalesced write-out: tile -> out (float4)
    const int gbase = coarse * NPB_C;
    for (int i = t; i < NPB_C * 8; i += AGG_THREADS) {
        const int node  = i >> 3;
        const int q     = i & 7;
        const int gnode = gbase + node;
        if (gnode < N_NODES) {
            const float4 val = *reinterpret_cast<const float4*>(
                tile + node * TSTRIDE + q * 4);
            reinterpret_cast<float4*>(out + (size_t)gnode * F_DIM)[q] = val;
        }
    }
}

// ---------------- fallback (R0): plain atomic scatter ----------------
__global__ __launch_bounds__(256) void gnn_scatter_atomic(
    const float* __restrict__ x, const int* __restrict__ src,
    const int* __restrict__ dst, const float* __restrict__ ew,
    const float* __restrict__ w_mp, float* __restrict__ out)
{
    const float w = w_mp[0];
    int gid = blockIdx.x * blockDim.x + threadIdx.x;
    int e = gid >> 3;
    int qq = (gid & 7) * 4;
    if (e >= N_EDGES) return;
    int s = src[e];
    int d = dst[e];
    float c = w * ew[e];
    const float4 xv = *reinterpret_cast<const float4*>(x + (size_t)s * F_DIM + qq);
    float* op = out + (size_t)d * F_DIM + qq;
    atomicAdd(op + 0, c * xv.x);
    atomicAdd(op + 1, c * xv.y);
    atomicAdd(op + 2, c * xv.z);
    atomicAdd(op + 3, c * xv.w);
}

extern "C" void kernel_launch(void* const* d_in, const int* in_sizes, int n_in,
                              void* d_out, int out_size, void* d_ws, size_t ws_size,
                              hipStream_t stream) {
    const float* x    = (const float*)d_in[0];
    const int*   ei   = (const int*)d_in[1];   // [2, E]: src row, then dst row
    const float* ew   = (const float*)d_in[2];
    const float* w_mp = (const float*)d_in[3];
    float* out = (float*)d_out;

    const int* src = ei;
    const int* dst = ei + N_EDGES;

    if (ws_size < WS_NEEDED) {
        hipMemsetAsync(d_out, 0, (size_t)out_size * sizeof(float), stream);
        int total = N_EDGES * 8;
        gnn_scatter_atomic<<<(total + 255) / 256, 256, 0, stream>>>(
            x, src, dst, ew, w_mp, out);
        return;
    }

    char* ws = (char*)d_ws;
    int*   gcursor = (int*)(ws + WS_CURSOR);
    uint2* records = (uint2*)(ws + WS_RECORDS);

    hipMemsetAsync(gcursor, 0, WS_ZERO, stream);
    bin_edges<<<BIN_BLOCKS, BIN_THREADS, 0, stream>>>(src, dst, ew, w_mp,
                                                      gcursor, records);
    scatter_lds<<<NB_C, AGG_THREADS, 0, stream>>>(gcursor, records, x, out);
    // scatter_lds writes every out element -> no d_out memset needed
}

// Round 8
// 121.811 us; speedup vs baseline: 3.8673x; 3.8673x over previous
//
#include <hip/hip_runtime.h>

// toy_gnn scatter-add: out[dst[e], f] += w_mp * edge_weight[e] * x[src[e], f]
// N=100000, E=1600000, F=32, fp32.
//
// Round 15: restore best-measured configuration (R9, 121.8us).
//   R14 post-mortem: LDS fp32 atomic accumulate = 382us kernel (51.2M
//   ds_add_f32 with 64 lanes collapsing onto 8 banks/instr). Generalized
//   lesson: LDS atomic accumulation is never the fast path here, native or
//   not. Full ledger of falsified theories at the 122us plateau: record
//   re-reads (R8), occupancy 16->32 waves (R9), cursor contention (R9),
//   bin store coalescing (R11), load-pipeline depth + tail removal (R13),
//   sort-free gather (R14), coop fusion (R10), persistent fusion (R12).
//   Three distinct gather structures and three distinct bin structures all
//   measure 121.8-123.7us -> both kernels sit at structure-invariant
//   floors. Gather's floor is algorithmic: every edge moves its full 128B
//   x-row across the fabric (E x 128B = 205MB/iter, irreducible by layout;
//   src-major moves the same bytes to the atomic side). Window fixed costs:
//   43.5us in-window workspace re-poison + memset + graph gaps ~= 50us.
//   122 ~= 50 fixed + ~35 gather@traffic-floor + ~30 bin + gaps.
//   This file is the R9 kernel pair verbatim (best measured: 121.78us).

constexpr int N_NODES = 100000;
constexpr int N_EDGES = 1600000;
constexpr int F_DIM   = 32;

// ---- binning (coarse) ----
constexpr int NPB_C = 256;                           // nodes per coarse bucket
constexpr int NB_C  = (N_NODES + NPB_C - 1) / NPB_C; // 391
constexpr int CAP_C = 4608;                          // mean 4096 + 8 sigma(64)

constexpr int CUR_STRIDE = 32;                       // ints; 128B per cursor line

constexpr int BIN_THREADS = 1024;                    // 16 waves/CU
constexpr int BIN_BLOCKS  = 256;                     // one per CU
constexpr int BIN_CHUNK   = N_EDGES / BIN_BLOCKS;    // 6250 (exact)
constexpr int BIN_EPT     = (BIN_CHUNK + BIN_THREADS - 1) / BIN_THREADS;  // 7

// ---- fused sort+gather ----
constexpr int AGG_THREADS = 1024;                    // 16 waves
constexpr int GRPT = (CAP_C + AGG_THREADS - 1) / AGG_THREADS;  // 5

// ---------------- workspace layout (bytes) ----------------
constexpr size_t WS_CURSOR  = 0;                     // NB_C padded cursors
constexpr size_t WS_RECORDS = 64 * 1024;             // NB_C*CAP_C uint2
constexpr size_t WS_NEEDED  = WS_RECORDS + (size_t)NB_C * CAP_C * 8;  // ~14.5 MB

__global__ __launch_bounds__(BIN_THREADS) void bin_edges(
    const int* __restrict__ src, const int* __restrict__ dst,
    const float* __restrict__ ew, const float* __restrict__ w_mp,
    int* __restrict__ gcursor, uint2* __restrict__ records)
{
    __shared__ int lhist[NB_C];
    __shared__ int lbase[NB_C];
    if (threadIdx.x < NB_C) lhist[threadIdx.x] = 0;
    __syncthreads();

    const float w = w_mp[0];
    const int base_e = blockIdx.x * BIN_CHUNK;
    const int e_end  = min(base_e + BIN_CHUNK, N_EDGES);
    int   bkt[BIN_EPT];
    uint2 rec[BIN_EPT];

    #pragma unroll
    for (int i = 0; i < BIN_EPT; ++i) {
        int e = base_e + threadIdx.x + i * BIN_THREADS;
        bkt[i] = -1;
        if (e < e_end) {
            int d = dst[e];
            int b = d >> 8;                     // coarse bucket (256 nodes)
            bkt[i] = b;
            rec[i].x = __float_as_uint(w * ew[e]);
            rec[i].y = (unsigned)src[e] | ((unsigned)(d & 255) << 24);
            atomicAdd(&lhist[b], 1);
        }
    }
    __syncthreads();

    if (threadIdx.x < NB_C) {
        int c = lhist[threadIdx.x];
        // padded cursor: one counter per 128B cacheline -> no false sharing
        int base = c ? atomicAdd(&gcursor[threadIdx.x * CUR_STRIDE], c) : 0;
        lbase[threadIdx.x] = threadIdx.x * CAP_C + base;
        lhist[threadIdx.x] = 0;
    }
    __syncthreads();

    #pragma unroll
    for (int i = 0; i < BIN_EPT; ++i) {
        int b = bkt[i];
        if (b >= 0) {
            int pos = lbase[b] + atomicAdd(&lhist[b], 1);
            if (pos < (b + 1) * CAP_C)          // overflow guard (8-sigma margin)
                records[pos] = rec[i];
        }
    }
}

__global__ __launch_bounds__(AGG_THREADS, 8) void sort_gather(
    const int*   __restrict__ gcursor,
    const uint2* __restrict__ records,
    const float* __restrict__ x,
    float*       __restrict__ out)
{
    __shared__ uint2 sorted[CAP_C];      // 36.9 KB node-sorted records
    __shared__ int   hist[NPB_C];
    __shared__ int   offs[NPB_C + 1];
    __shared__ int   cursor[NPB_C];

    const int coarse = blockIdx.x;
    const int t      = threadIdx.x;

    if (t < NPB_C) hist[t] = 0;
    __syncthreads();

    // --- single global pass: records -> registers, histogram nodes ---
    const int rbase = coarse * CAP_C;
    const int cnt   = min(gcursor[coarse * CUR_STRIDE], CAP_C);

    uint2 rec[GRPT];
    #pragma unroll
    for (int i = 0; i < GRPT; ++i) {
        int j = t + i * AGG_THREADS;
        rec[i].y = 0xFFFFFFFFu;             // "empty" (src < 2^24 -> unambiguous)
        if (j < cnt) {
            rec[i] = records[rbase + j];
            atomicAdd(&hist[rec[i].y >> 24], 1);
        }
    }
    __syncthreads();

    // --- exclusive scan of 256 counters (wave 0, 4 per lane) ---
    if (t < 64) {
        const int b4 = t * 4;
        int h0 = hist[b4], h1 = hist[b4 + 1], h2 = hist[b4 + 2], h3 = hist[b4 + 3];
        int s   = h0 + h1 + h2 + h3;
        int inc = s;
        #pragma unroll
        for (int d = 1; d < 64; d <<= 1) {
            int o = __shfl_up(inc, d, 64);
            if (t >= d) inc += o;
        }
        int base = inc - s;                 // exclusive prefix of 4-groups
        offs[b4]     = base;
        offs[b4 + 1] = base + h0;
        offs[b4 + 2] = base + h0 + h1;
        offs[b4 + 3] = base + h0 + h1 + h2;
        cursor[b4]     = base;
        cursor[b4 + 1] = base + h0;
        cursor[b4 + 2] = base + h0 + h1;
        cursor[b4 + 3] = base + h0 + h1 + h2;
        if (t == 63) offs[NPB_C] = inc;
    }
    __syncthreads();

    // --- scatter registers -> sorted LDS (counting sort by node, 8 bits) ---
    #pragma unroll
    for (int i = 0; i < GRPT; ++i) {
        if (rec[i].y != 0xFFFFFFFFu) {
            int slot = atomicAdd(&cursor[rec[i].y >> 24], 1);
            sorted[slot] = rec[i];
        }
    }
    __syncthreads();

    // --- gather: 8 threads/node, register acc, 4-way unrolled x-loads ---
    const int qq = (t & 7) * 4;
    #pragma unroll
    for (int p = 0; p < 2; ++p) {
        const int node  = p * (AGG_THREADS / 8) + (t >> 3);
        const int gnode = coarse * NPB_C + node;
        if (gnode >= N_NODES) continue;

        int j  = offs[node];
        int je = offs[node + 1];
        float4 acc = make_float4(0.f, 0.f, 0.f, 0.f);

        for (; j + 4 <= je; j += 4) {
            uint2 r0 = sorted[j + 0];
            uint2 r1 = sorted[j + 1];
            uint2 r2 = sorted[j + 2];
            uint2 r3 = sorted[j + 3];
            const float4 v0 = *reinterpret_cast<const float4*>(
                x + (size_t)(r0.y & 0xFFFFFFu) * F_DIM + qq);
            const float4 v1 = *reinterpret_cast<const float4*>(
                x + (size_t)(r1.y & 0xFFFFFFu) * F_DIM + qq);
            const float4 v2 = *reinterpret_cast<const float4*>(
                x + (size_t)(r2.y & 0xFFFFFFu) * F_DIM + qq);
            const float4 v3 = *reinterpret_cast<const float4*>(
                x + (size_t)(r3.y & 0xFFFFFFu) * F_DIM + qq);
            float c0 = __uint_as_float(r0.x), c1 = __uint_as_float(r1.x);
            float c2 = __uint_as_float(r2.x), c3 = __uint_as_float(r3.x);
            acc.x += c0 * v0.x + c1 * v1.x + c2 * v2.x + c3 * v3.x;
            acc.y += c0 * v0.y + c1 * v1.y + c2 * v2.y + c3 * v3.y;
            acc.z += c0 * v0.z + c1 * v1.z + c2 * v2.z + c3 * v3.z;
            acc.w += c0 * v0.w + c1 * v1.w + c2 * v2.w + c3 * v3.w;
        }
        for (; j < je; ++j) {
            uint2 r = sorted[j];
            float c = __uint_as_float(r.x);
            const float4 v = *reinterpret_cast<const float4*>(
                x + (size_t)(r.y & 0xFFFFFFu) * F_DIM + qq);
            acc.x += c * v.x;
            acc.y += c * v.y;
            acc.z += c * v.z;
            acc.w += c * v.w;
        }
        *reinterpret_cast<float4*>(out + (size_t)gnode * F_DIM + qq) = acc;
    }
}

// ---------------- fallback (R0): plain atomic scatter ----------------
__global__ __launch_bounds__(256) void gnn_scatter_atomic(
    const float* __restrict__ x, const int* __restrict__ src,
    const int* __restrict__ dst, const float* __restrict__ ew,
    const float* __restrict__ w_mp, float* __restrict__ out)
{
    const float w = w_mp[0];
    int gid = blockIdx.x * blockDim.x + threadIdx.x;
    int e = gid >> 3;
    int qq = (gid & 7) * 4;
    if (e >= N_EDGES) return;
    int s = src[e];
    int d = dst[e];
    float c = w * ew[e];
    const float4 xv = *reinterpret_cast<const float4*>(x + (size_t)s * F_DIM + qq);
    float* op = out + (size_t)d * F_DIM + qq;
    atomicAdd(op + 0, c * xv.x);
    atomicAdd(op + 1, c * xv.y);
    atomicAdd(op + 2, c * xv.z);
    atomicAdd(op + 3, c * xv.w);
}

extern "C" void kernel_launch(void* const* d_in, const int* in_sizes, int n_in,
                              void* d_out, int out_size, void* d_ws, size_t ws_size,
                              hipStream_t stream) {
    const float* x    = (const float*)d_in[0];
    const int*   ei   = (const int*)d_in[1];   // [2, E]: src row, then dst row
    const float* ew   = (const float*)d_in[2];
    const float* w_mp = (const float*)d_in[3];
    float* out = (float*)d_out;

    const int* src = ei;
    const int* dst = ei + N_EDGES;

    if (ws_size < WS_NEEDED) {
        hipMemsetAsync(d_out, 0, (size_t)out_size * sizeof(float), stream);
        int total = N_EDGES * 8;
        gnn_scatter_atomic<<<(total + 255) / 256, 256, 0, stream>>>(
            x, src, dst, ew, w_mp, out);
        return;
    }

    char* ws = (char*)d_ws;
    int*   gcursor = (int*)(ws + WS_CURSOR);
    uint2* records = (uint2*)(ws + WS_RECORDS);

    hipMemsetAsync(gcursor, 0, NB_C * CUR_STRIDE * sizeof(int), stream);
    bin_edges<<<BIN_BLOCKS, BIN_THREADS, 0, stream>>>(src, dst, ew, w_mp,
                                                      gcursor, records);
    sort_gather<<<NB_C, AGG_THREADS, 0, stream>>>(gcursor, records, x, out);
    // sort_gather writes every out element -> no d_out memset needed
}